// Round 1
// baseline (244.351 us; speedup 1.0000x reference)
//
#include <hip/hip_runtime.h>

#define WS 128
#define HALF 64
#define HW (1024 * 1024)
#define PLANE 8388608   // C * WS * WS = 512 * 16384
#define DH 16
#define E 6

__global__ __launch_bounds__(256) void instanseg_fused(
    const float* __restrict__ x,        // (6, 1024, 1024)
    const float* __restrict__ sigma,    // (1, 1024, 1024)
    const float* __restrict__ c,        // (512, 6)
    const float* __restrict__ W1,       // (7, 16)
    const float* __restrict__ b1,       // (16)
    const float* __restrict__ W2,       // (16, 16)
    const float* __restrict__ b2,       // (16)
    const float* __restrict__ W3,       // (16, 1)
    const float* __restrict__ b3,       // (1)
    const int*   __restrict__ cent,     // (512, 2)
    float* __restrict__ out)            // prob plane + 3 iidd planes (as float)
{
    const int cid = blockIdx.y;
    const int idx = blockIdx.x * 256 + threadIdx.x;   // 0 .. 16383
    const int py = idx >> 7;
    const int px = idx & 127;

    // clipped centroid (uniform per block -> scalar loads)
    int cy = cent[2 * cid];
    int cx = cent[2 * cid + 1];
    cy = min(max(cy, HALF), 1024 - HALF);
    cx = min(max(cx, HALF), 1024 - HALF);

    const int row = cy - HALF + py;
    const int col = cx - HALF + px;
    const int src = row * 1024 + col;

    // gather 7 channels; subtract centroid embedding on the E x-channels
    float g[E + 1];
#pragma unroll
    for (int e = 0; e < E; ++e)
        g[e] = x[e * HW + src] - c[cid * E + e];
    g[E] = sigma[src];

    // layer 1: 7 -> 16, relu
    float h1[DH];
#pragma unroll
    for (int j = 0; j < DH; ++j) {
        float a = b1[j];
#pragma unroll
        for (int e = 0; e < E + 1; ++e)
            a = fmaf(g[e], W1[e * DH + j], a);
        h1[j] = fmaxf(a, 0.0f);
    }

    // layer 2: 16 -> 16, relu
    float h2[DH];
#pragma unroll
    for (int j = 0; j < DH; ++j) {
        float a = b2[j];
#pragma unroll
        for (int i = 0; i < DH; ++i)
            a = fmaf(h1[i], W2[i * DH + j], a);
        h2[j] = fmaxf(a, 0.0f);
    }

    // layer 3: 16 -> 1, sigmoid
    float o = b3[0];
#pragma unroll
    for (int i = 0; i < DH; ++i)
        o = fmaf(h2[i], W3[i], o);
    const float prob = 1.0f / (1.0f + __expf(-o));

    const int n = cid * (WS * WS) + idx;
    out[n]             = prob;
    out[PLANE + n]     = (float)cid;   // inst
    out[2 * PLANE + n] = (float)row;   // mesh rows
    out[3 * PLANE + n] = (float)col;   // mesh cols
}

extern "C" void kernel_launch(void* const* d_in, const int* in_sizes, int n_in,
                              void* d_out, int out_size, void* d_ws, size_t ws_size,
                              hipStream_t stream) {
    const float* x     = (const float*)d_in[0];
    const float* sigma = (const float*)d_in[1];
    const float* c     = (const float*)d_in[2];
    const float* W1    = (const float*)d_in[3];
    const float* b1    = (const float*)d_in[4];
    const float* W2    = (const float*)d_in[5];
    const float* b2    = (const float*)d_in[6];
    const float* W3    = (const float*)d_in[7];
    const float* b3    = (const float*)d_in[8];
    const int*   cent  = (const int*)d_in[9];
    float* out = (float*)d_out;

    dim3 grid(64, 512);   // 64 chunks of 256 px per 128x128 window, 512 centroids
    dim3 block(256);
    instanseg_fused<<<grid, block, 0, stream>>>(
        x, sigma, c, W1, b1, W2, b2, W3, b3, cent, out);
}